// Round 2
// baseline (157.985 us; speedup 1.0000x reference)
//
#include <hip/hip_runtime.h>
#include <hip/hip_fp16.h>
#include <math.h>

// Problem constants (B=8, S=2048, T=128)
#define S_LEN 2048
#define T_DIM 128
#define BM 128               // tokens per block (m-range)  [R2: was 64]
#define TN 32                // output cols per block       [R2: was 64]
#define NBLK 512             // (mb 0..127) x (th 0..3); th on bits1-2 -> XCD-pinned
#define TOKR 132             // tokT2 row stride in f16 (264 B, 8B-aligned for b64 reads)

typedef _Float16 half8 __attribute__((ext_vector_type(8)));
typedef _Float16 half4t __attribute__((ext_vector_type(4)));
typedef float floatx16 __attribute__((ext_vector_type(16)));

// Fast exact tanh: 1 - 2/(1+e^{2x})
__device__ __forceinline__ float tanh_fast(float x) {
  return 1.0f - __fdividef(2.0f, 1.0f + __expf(2.0f * x));
}

// ---------------------------------------------------------------------------
// Kernel A (grid 3072x256): fused prep (unchanged):
//  blocks 0..1023  : W fp32 [t][p][q] -> W16f fp16 MFMA-fragment order
//    W16f[((p*4 + tc)*8 + kc)*512 + lh2*256 + (t&31)*8 + j]
//  blocks 1024..3071: out[b,i,t] = sum(w_red)*tanh(b_comp[t]) + b_red
// ---------------------------------------------------------------------------
__global__ __launch_bounds__(256) void prep_kernel(
    const float* __restrict__ W, const float* __restrict__ w_red,
    const float* __restrict__ b_comp, const float* __restrict__ b_red,
    _Float16* __restrict__ W16f, float* __restrict__ out) {
  const int blk = blockIdx.x;
  const int tid = threadIdx.x;
  if (blk < 1024) {
    const int t = blk >> 3;
    const int qh = (blk >> 2) & 1;
    const int it = blk & 3;
    const int tc = t >> 5, tl = t & 31;
    const int e8 = it * 256 + tid;        // 0..1023 over [p(128)][q-chunk(8)]
    const int p = e8 >> 3;
    const int q = qh * 64 + (e8 & 7) * 8;
    const float* src = W + (size_t)t * 16384 + (size_t)p * 128 + q;
    const float4 v0 = *(const float4*)src;
    const float4 v1 = *(const float4*)(src + 4);
    half8 h;
    h[0] = (_Float16)v0.x; h[1] = (_Float16)v0.y;
    h[2] = (_Float16)v0.z; h[3] = (_Float16)v0.w;
    h[4] = (_Float16)v1.x; h[5] = (_Float16)v1.y;
    h[6] = (_Float16)v1.z; h[7] = (_Float16)v1.w;
    const int kc = q >> 4, lh2 = (q >> 3) & 1;
    *(half8*)(W16f + ((size_t)((p * 4 + tc) * 8 + kc)) * 512 + lh2 * 256 + tl * 8) = h;
  } else {
    __shared__ float red4[4];
    float part = 0.f;
#pragma unroll
    for (int i = 0; i < 8; ++i) part += w_red[tid * 8 + i];
#pragma unroll
    for (int off = 32; off > 0; off >>= 1) part += __shfl_down(part, off, 64);
    if ((tid & 63) == 0) red4[tid >> 6] = part;
    __syncthreads();
    const float Sw = red4[0] + red4[1] + red4[2] + red4[3];
    const float br = b_red[0];
    const size_t base = (size_t)(blk - 1024) * 1024 + (size_t)tid * 4;
    const int t0 = (int)(base & 127);
    float4 v;
    v.x = Sw * tanh_fast(b_comp[t0 + 0]) + br;
    v.y = Sw * tanh_fast(b_comp[t0 + 1]) + br;
    v.z = Sw * tanh_fast(b_comp[t0 + 2]) + br;
    v.w = Sw * tanh_fast(b_comp[t0 + 3]) + br;
    *(float4*)(out + base) = v;
  }
}

// ---------------------------------------------------------------------------
// Kernel B: MFMA main, BM=128 x TN=32 retile.
// THEORY (R2): at BM=64/TN=64, each 1KB B-fragment fed only 2 m-tiles ->
// 512 B of W16f through L1 per MFMA -> 64 B/cyc/CU at MFMA saturation =
// 100% of the TCP/L2 per-CU return budget (and 37 TB/s aggregate L2 at
// floor, above the 34.5 ceiling) -> structurally capped near 46% MfmaUtil.
// BM=128/TN=32: one B-fragment feeds 4 MFMAs (4 m-tiles) -> 256 B/MFMA ->
// 32 B/cyc/CU (50% of path), aggregate L2 at floor ~18.6 TB/s (54%).
// acc stays 4x16 = 64 AGPRs -> 4 waves/SIMD; bf prefetch regs halve.
// th = (blk>>1)&3 (bits 1-2, fixed per XCD since XCD = blk&7): each W16f
// 1MB quarter L2-resident on its XCD pair. pstag now full-rank: all 64
// same-XCD blocks get distinct p-phases (2 apart); CU-mates differ by 64
// via dispatch rounds. 2 blocks/CU (LDS 66.5KB), 8 waves = kh 0..7.
// v_mfma_f32_32x32x16_f16: A lane m=l&31, k=(l>>5)*8+j; B n=l&31 same k;
// C/D col=l&31, row=(r&3)+8*(r>>2)+4*(l>>5)   [m74/m101-verified]
// ---------------------------------------------------------------------------
__global__ __launch_bounds__(512, 4) void main_kernel(
    const float* __restrict__ tok, const int* __restrict__ heads,
    const _Float16* __restrict__ W16f, const float* __restrict__ b_comp,
    const float* __restrict__ w_red, float* __restrict__ out) {
  __shared__ _Float16 tokT2[128 * TOKR];  // 33.8 KB: [p][(m&31)*4 + (m>>5)]
  __shared__ float red[2][BM * TN];       // 2 x 16 KB: kh-parity planes [m][t_loc]

  const int tid = threadIdx.x;
  const int lane = tid & 63;
  const int kh = tid >> 6;   // wave = q-chunk of 16 (kc index)
  const int l31 = lane & 31;
  const int lh = lane >> 5;
  const int blk = blockIdx.x;
  const int th = (blk >> 1) & 3;                    // t-quarter, bits1-2 (XCD-pinned)
  const int mb = ((blk >> 3) << 1) | (blk & 1);     // 0..127
  // Full-rank p-phase stagger: same-XCD blocks (blk>>3 = 0..63) all get
  // distinct phases 2 apart; CU-mates (dispatch rounds 1/2) differ by 64.
  const int pstag = ((blk >> 3) * 2) & 127;
  const size_t tokbase = (size_t)mb * BM * T_DIM;

  // ---- stage tokT2: coalesced float4 reads, transposed f16 writes ----
#pragma unroll
  for (int it = 0; it < 8; ++it) {
    const int f = it * 512 + tid;   // 0..4095 float4s over [m(128)][p4(32)]
    const int m = f >> 5;
    const int p0 = (f & 31) * 4;
    const float4 v = *(const float4*)(tok + tokbase + (size_t)m * 128 + p0);
    const int mi = (m & 31) * 4 + (m >> 5);
    tokT2[(p0 + 0) * TOKR + mi] = (_Float16)v.x;
    tokT2[(p0 + 1) * TOKR + mi] = (_Float16)v.y;
    tokT2[(p0 + 2) * TOKR + mi] = (_Float16)v.z;
    tokT2[(p0 + 3) * TOKR + mi] = (_Float16)v.w;
  }

  // ---- per-lane h fragments: h16[mh], m = mh*32 + l31, q0 = kh*16 + lh*8 ----
  half8 h16[4];
#pragma unroll
  for (int mh = 0; mh < 4; ++mh) {
    const int m = mh * 32 + l31;
    const int q0 = kh * 16 + lh * 8;
    const float4 v0 = *(const float4*)(tok + tokbase + (size_t)m * 128 + q0);
    const float4 v1 = *(const float4*)(tok + tokbase + (size_t)m * 128 + q0 + 4);
    h16[mh][0] = (_Float16)tanh_fast(v0.x);
    h16[mh][1] = (_Float16)tanh_fast(v0.y);
    h16[mh][2] = (_Float16)tanh_fast(v0.z);
    h16[mh][3] = (_Float16)tanh_fast(v0.w);
    h16[mh][4] = (_Float16)tanh_fast(v1.x);
    h16[mh][5] = (_Float16)tanh_fast(v1.y);
    h16[mh][6] = (_Float16)tanh_fast(v1.z);
    h16[mh][7] = (_Float16)tanh_fast(v1.w);
  }
  __syncthreads();  // tokT2 ready; last barrier before the p-loop

  // Wave's B-fragment offset: tc = th, kc = kh (single t-tile now)
  const int off = ((th * 8 + kh) << 9) + lane * 8;

  floatx16 acc[4];  // [mh] -> 64 AGPRs
#pragma unroll
  for (int mh = 0; mh < 4; ++mh)
#pragma unroll
    for (int r = 0; r < 16; ++r) acc[mh][r] = 0.f;

  half8 bf0, bf1, bf2;
  half4t tk0, tk1, tk2;

  // Logical p -> physical pp via per-block phase rotation (uniform/scalar).
  auto loadB = [&](half8& bf, int p) {
    const int pp = (p + pstag) & 127;
    bf = *(const half8*)(W16f + (size_t)pp * 16384 + off);
  };
  auto loadT = [&](half4t& tk, int p) {
    const int pp = (p + pstag) & 127;
    tk = *(const half4t*)(tokT2 + pp * TOKR + l31 * 4);
  };

  auto compute = [&](half8 bf, half4t tk) {
#pragma unroll
    for (int mh = 0; mh < 4; ++mh) {
      half8 a = h16[mh] * tk[mh];   // 4 v_pk_mul each
      acc[mh] = __builtin_amdgcn_mfma_f32_32x32x16_f16(a, bf, acc[mh], 0, 0, 0);
    }
  };

  // 3-buffer, distance-2 software pipeline over 128 p (no barriers).
  loadB(bf0, 0);  loadT(tk0, 0);
  loadB(bf1, 1);  loadT(tk1, 1);
  for (int p = 0; p < 126; p += 3) {
    loadB(bf2, p + 2);  loadT(tk2, p + 2);
    compute(bf0, tk0);
    loadB(bf0, p + 3);  loadT(tk0, p + 3);
    compute(bf1, tk1);
    loadB(bf1, p + 4);  loadT(tk1, p + 4);
    compute(bf2, tk2);
  }
  compute(bf0, tk0);  // p = 126
  compute(bf1, tk1);  // p = 127

  // ---- kh reduction: parity -> plane, 4 serial phases (2 waves/phase) ----
  __syncthreads();
  {
    float* R = &red[kh & 1][0];
    const int g = kh >> 1;
#pragma unroll
    for (int phase = 0; phase < 4; ++phase) {
      if (g == phase) {
#pragma unroll
        for (int mh = 0; mh < 4; ++mh) {
#pragma unroll
          for (int r = 0; r < 16; ++r) {
            const int m_loc = mh * 32 + (r & 3) + 8 * (r >> 2) + 4 * lh;
            const int addr = m_loc * TN + l31;
            if (phase == 0) R[addr] = acc[mh][r];
            else            R[addr] += acc[mh][r];
          }
        }
      }
      __syncthreads();
    }
  }

  // ---- inline scatter epilogue: 512 threads, 8 m's x 1 t each ----
  const int t_loc = tid & 31;
  const int mgrp = tid >> 5;  // 0..15
  const int t = th * 32 + t_loc;
  const float bc = b_comp[t];
  const float tb = tanh_fast(bc);
#pragma unroll 4
  for (int mi = 0; mi < 8; ++mi) {
    const int m_loc = mi * 16 + mgrp;
    const int gm = mb * BM + m_loc;
    const int head = heads[gm];
    const float wr = w_red[gm & 2047];
    const float v = red[0][m_loc * TN + t_loc] + red[1][m_loc * TN + t_loc] + bc;
    atomicAdd(out + ((size_t)(gm >> 11) * S_LEN + head) * T_DIM + t,
              wr * (tanh_fast(v) - tb));
  }
}

// ---------------------------------------------------------------------------
extern "C" void kernel_launch(void* const* d_in, const int* in_sizes, int n_in,
                              void* d_out, int out_size, void* d_ws, size_t ws_size,
                              hipStream_t stream) {
  const float* tok    = (const float*)d_in[0];
  // d_in[1] = dep_embeddings: dead input (source bug), unused
  const int*   heads  = (const int*)d_in[2];
  const float* W      = (const float*)d_in[3];
  const float* b_comp = (const float*)d_in[4];
  const float* w_red  = (const float*)d_in[5];
  const float* b_red  = (const float*)d_in[6];
  float* out = (float*)d_out;

  _Float16* W16f = (_Float16*)d_ws;  // 4 MB, MFMA-fragment order

  prep_kernel<<<3072, 256, 0, stream>>>(W, w_red, b_comp, b_red, W16f, out);
  main_kernel<<<NBLK, 512, 0, stream>>>(tok, heads, W16f, b_comp, w_red, out);
}

// Round 3
// 151.628 us; speedup vs baseline: 1.0419x; 1.0419x over previous
//
#include <hip/hip_runtime.h>
#include <hip/hip_fp16.h>
#include <math.h>

// Problem constants (B=8, S=2048, T=128)
#define S_LEN 2048
#define T_DIM 128
#define BM 128               // tokens per block (m-range): Mt=4 m-tiles
#define TN 64                // output cols per block: Nt=2 t-tiles
#define NBLK 256             // (mb 0..127) x (th 0..1); th on bit0 -> XCD-pinned
#define TOKR 132             // tokT2 row stride in f16 (264 B)

typedef _Float16 half8 __attribute__((ext_vector_type(8)));
typedef _Float16 half4t __attribute__((ext_vector_type(4)));
typedef float floatx16 __attribute__((ext_vector_type(16)));

// Fast exact tanh: 1 - 2/(1+e^{2x})
__device__ __forceinline__ float tanh_fast(float x) {
  return 1.0f - __fdividef(2.0f, 1.0f + __expf(2.0f * x));
}

// ---------------------------------------------------------------------------
// Kernel A (grid 3072x256): fused prep (unchanged):
//  blocks 0..1023  : W fp32 [t][p][q] -> W16f fp16 MFMA-fragment order
//    W16f[((p*4 + tc)*8 + kc)*512 + lh2*256 + (t&31)*8 + j]
//  blocks 1024..3071: out[b,i,t] = sum(w_red)*tanh(b_comp[t]) + b_red
// ---------------------------------------------------------------------------
__global__ __launch_bounds__(256) void prep_kernel(
    const float* __restrict__ W, const float* __restrict__ w_red,
    const float* __restrict__ b_comp, const float* __restrict__ b_red,
    _Float16* __restrict__ W16f, float* __restrict__ out) {
  const int blk = blockIdx.x;
  const int tid = threadIdx.x;
  if (blk < 1024) {
    const int t = blk >> 3;
    const int qh = (blk >> 2) & 1;
    const int it = blk & 3;
    const int tc = t >> 5, tl = t & 31;
    const int e8 = it * 256 + tid;        // 0..1023 over [p(128)][q-chunk(8)]
    const int p = e8 >> 3;
    const int q = qh * 64 + (e8 & 7) * 8;
    const float* src = W + (size_t)t * 16384 + (size_t)p * 128 + q;
    const float4 v0 = *(const float4*)src;
    const float4 v1 = *(const float4*)(src + 4);
    half8 h;
    h[0] = (_Float16)v0.x; h[1] = (_Float16)v0.y;
    h[2] = (_Float16)v0.z; h[3] = (_Float16)v0.w;
    h[4] = (_Float16)v1.x; h[5] = (_Float16)v1.y;
    h[6] = (_Float16)v1.z; h[7] = (_Float16)v1.w;
    const int kc = q >> 4, lh2 = (q >> 3) & 1;
    *(half8*)(W16f + ((size_t)((p * 4 + tc) * 8 + kc)) * 512 + lh2 * 256 + tl * 8) = h;
  } else {
    __shared__ float red4[4];
    float part = 0.f;
#pragma unroll
    for (int i = 0; i < 8; ++i) part += w_red[tid * 8 + i];
#pragma unroll
    for (int off = 32; off > 0; off >>= 1) part += __shfl_down(part, off, 64);
    if ((tid & 63) == 0) red4[tid >> 6] = part;
    __syncthreads();
    const float Sw = red4[0] + red4[1] + red4[2] + red4[3];
    const float br = b_red[0];
    const size_t base = (size_t)(blk - 1024) * 1024 + (size_t)tid * 4;
    const int t0 = (int)(base & 127);
    float4 v;
    v.x = Sw * tanh_fast(b_comp[t0 + 0]) + br;
    v.y = Sw * tanh_fast(b_comp[t0 + 1]) + br;
    v.z = Sw * tanh_fast(b_comp[t0 + 2]) + br;
    v.w = Sw * tanh_fast(b_comp[t0 + 3]) + br;
    *(float4*)(out + base) = v;
  }
}

// ---------------------------------------------------------------------------
// Kernel B: MFMA main, BM=128 x TN=64 (Mt=4, Nt=2).
// R3 THEORY: per-MFMA cost = {4/Nt pk_mul VALU, 1024/Mt B of W16f L1 traffic}.
//  R1 (2,2): 2 pk_mul + 512 B -> L1 path 100% of 64 B/cyc/CU at saturation.
//  R2 (4,1): 4 pk_mul + 256 B -> VALU doubled, staging doubled -> regressed.
//  R3 (4,2): 2 pk_mul + 256 B -> R1's VALU ratio, half the L1 demand.
// Cost: acc = 8 floatx16 = 128 AGPR -> ~200 unified regs -> 2 waves/SIMD,
// 1 block/CU (LDS 97 KB). Per-wave MFMA ILP = 8 -> pipe saturable at 2 waves
// (HK 256-sq precedent); distance-2 prefetch lead ~1024 cyc >> L2 latency.
// Staging-write bank conflict (R2: 8-way, 1.83M cyc) fixed by XOR swizzle:
// col = mi ^ (((p+(p>>3))&7)<<2); write becomes 2-way (free), read stays one
// ds_read_b64 with the same wave-uniform XOR. First 2 W16f prefetches issue
// BEFORE the barrier (global->reg only) to overlap staging drain.
// 256 blocks = 1/CU; th = blk&1 (XCD-pinned: each XCD reads one 2MB half);
// pstag full-rank per XCD (32 phases, 4 apart).
// v_mfma_f32_32x32x16_f16: A lane m=l&31, k=(l>>5)*8+j; B n=l&31 same k;
// C/D col=l&31, row=(r&3)+8*(r>>2)+4*(l>>5)   [m74/m101-verified]
// ---------------------------------------------------------------------------
__global__ __launch_bounds__(512, 2) void main_kernel(
    const float* __restrict__ tok, const int* __restrict__ heads,
    const _Float16* __restrict__ W16f, const float* __restrict__ b_comp,
    const float* __restrict__ w_red, float* __restrict__ out) {
  __shared__ _Float16 tokT2[128 * TOKR];  // 33.8 KB: [p][ (mi ^ swz(p)) ]
  __shared__ float red[2][BM * TN];       // 2 x 32 KB: kh-parity planes [m][t_loc]

  const int tid = threadIdx.x;
  const int lane = tid & 63;
  const int kh = tid >> 6;   // wave = q-chunk of 16 (kc index)
  const int l31 = lane & 31;
  const int lh = lane >> 5;
  const int blk = blockIdx.x;
  const int th = blk & 1;                 // t-half, bit0 (XCD-pinned: XCD=blk&7)
  const int mb = blk >> 1;                // 0..127
  // Full-rank p-phase stagger per XCD: same-XCD blocks (blk>>3 = 0..31)
  // get 32 distinct phases, 4 apart.
  const int pstag = ((blk >> 3) * 4) & 127;
  const size_t tokbase = (size_t)mb * BM * T_DIM;

  // ---- stage tokT2: coalesced float4 reads, swizzled transposed f16 writes --
#pragma unroll
  for (int it = 0; it < 8; ++it) {
    const int f = it * 512 + tid;   // 0..4095 float4s over [m(128)][p4(32)]
    const int m = f >> 5;
    const int p0 = (f & 31) * 4;
    const float4 v = *(const float4*)(tok + tokbase + (size_t)m * 128 + p0);
    const int mi = (m & 31) * 4 + (m >> 5);
    const float vv[4] = {v.x, v.y, v.z, v.w};
#pragma unroll
    for (int jj = 0; jj < 4; ++jj) {
      const int p = p0 + jj;
      const int col = mi ^ (((p + (p >> 3)) & 7) << 2);
      tokT2[p * TOKR + col] = (_Float16)vv[jj];
    }
  }

  // ---- per-lane h fragments: h16[mh], m = mh*32 + l31, q0 = kh*16 + lh*8 ----
  half8 h16[4];
#pragma unroll
  for (int mh = 0; mh < 4; ++mh) {
    const int m = mh * 32 + l31;
    const int q0 = kh * 16 + lh * 8;
    const float4 v0 = *(const float4*)(tok + tokbase + (size_t)m * 128 + q0);
    const float4 v1 = *(const float4*)(tok + tokbase + (size_t)m * 128 + q0 + 4);
    h16[mh][0] = (_Float16)tanh_fast(v0.x);
    h16[mh][1] = (_Float16)tanh_fast(v0.y);
    h16[mh][2] = (_Float16)tanh_fast(v0.z);
    h16[mh][3] = (_Float16)tanh_fast(v0.w);
    h16[mh][4] = (_Float16)tanh_fast(v1.x);
    h16[mh][5] = (_Float16)tanh_fast(v1.y);
    h16[mh][6] = (_Float16)tanh_fast(v1.z);
    h16[mh][7] = (_Float16)tanh_fast(v1.w);
  }

  // Wave's B-fragment offsets: tc = th*2 + tt, kc = kh
  int off[2];
#pragma unroll
  for (int tt = 0; tt < 2; ++tt)
    off[tt] = (((th * 2 + tt) * 8 + kh) << 9) + lane * 8;

  half8 bf0[2], bf1[2], bf2[2];
  half4t tk0, tk1, tk2;

  auto loadB = [&](half8 (&bf)[2], int p) {
    const int pp = (p + pstag) & 127;
    const _Float16* wp = W16f + (size_t)pp * 16384;
    bf[0] = *(const half8*)(wp + off[0]);
    bf[1] = *(const half8*)(wp + off[1]);
  };
  auto loadT = [&](half4t& tk, int p) {
    const int pp = (p + pstag) & 127;
    const int col = (l31 * 4) ^ (((pp + (pp >> 3)) & 7) << 2);
    tk = *(const half4t*)(tokT2 + pp * TOKR + col);
  };

  // Issue first W16f prefetches before the barrier (global->reg only):
  // their L2 latency overlaps the LDS staging drain + barrier.
  loadB(bf0, 0);
  loadB(bf1, 1);

  floatx16 acc[4][2];  // [mh][tt] -> 128 AGPRs
#pragma unroll
  for (int mh = 0; mh < 4; ++mh)
#pragma unroll
    for (int tt = 0; tt < 2; ++tt)
#pragma unroll
      for (int r = 0; r < 16; ++r) acc[mh][tt][r] = 0.f;

  __syncthreads();  // tokT2 ready; last barrier before the p-loop

  auto compute = [&](half8 (&bf)[2], half4t tk) {
#pragma unroll
    for (int mh = 0; mh < 4; ++mh) {
      half8 a = h16[mh] * tk[mh];   // 4 v_pk_mul each, feeds 2 MFMA
      acc[mh][0] = __builtin_amdgcn_mfma_f32_32x32x16_f16(a, bf[0], acc[mh][0], 0, 0, 0);
      acc[mh][1] = __builtin_amdgcn_mfma_f32_32x32x16_f16(a, bf[1], acc[mh][1], 0, 0, 0);
    }
  };

  // 3-buffer, distance-2 software pipeline over 128 p (no barriers).
  loadT(tk0, 0);
  loadT(tk1, 1);
  for (int p = 0; p < 126; p += 3) {
    loadB(bf2, p + 2);  loadT(tk2, p + 2);
    compute(bf0, tk0);
    loadB(bf0, p + 3);  loadT(tk0, p + 3);
    compute(bf1, tk1);
    loadB(bf1, p + 4);  loadT(tk1, p + 4);
    compute(bf2, tk2);
  }
  compute(bf0, tk0);  // p = 126
  compute(bf1, tk1);  // p = 127

  // ---- kh reduction: parity -> plane, 4 serial phases (2 waves/phase) ----
  __syncthreads();
  {
    float* R = &red[kh & 1][0];
    const int g = kh >> 1;
#pragma unroll
    for (int phase = 0; phase < 4; ++phase) {
      if (g == phase) {
#pragma unroll
        for (int mh = 0; mh < 4; ++mh)
#pragma unroll
          for (int tt = 0; tt < 2; ++tt) {
            const int t_loc = tt * 32 + l31;
#pragma unroll
            for (int r = 0; r < 16; ++r) {
              const int m_loc = mh * 32 + (r & 3) + 8 * (r >> 2) + 4 * lh;
              const int addr = m_loc * TN + t_loc;
              if (phase == 0) R[addr] = acc[mh][tt][r];
              else            R[addr] += acc[mh][tt][r];
            }
          }
      }
      __syncthreads();
    }
  }

  // ---- inline scatter epilogue: 512 threads, 16 m's x 1 t each ----
  const int t_loc = tid & 63;
  const int mgrp = tid >> 6;  // 0..7 (wave-uniform -> scalar heads/w_red loads)
  const int t = th * 64 + t_loc;
  const float bc = b_comp[t];
  const float tb = tanh_fast(bc);
#pragma unroll 4
  for (int mi = 0; mi < 16; ++mi) {
    const int m_loc = mi * 8 + mgrp;
    const int gm = mb * BM + m_loc;
    const int head = heads[gm];
    const float wr = w_red[gm & 2047];
    const float v = red[0][m_loc * TN + t_loc] + red[1][m_loc * TN + t_loc] + bc;
    atomicAdd(out + ((size_t)(gm >> 11) * S_LEN + head) * T_DIM + t,
              wr * (tanh_fast(v) - tb));
  }
}

// ---------------------------------------------------------------------------
extern "C" void kernel_launch(void* const* d_in, const int* in_sizes, int n_in,
                              void* d_out, int out_size, void* d_ws, size_t ws_size,
                              hipStream_t stream) {
  const float* tok    = (const float*)d_in[0];
  // d_in[1] = dep_embeddings: dead input (source bug), unused
  const int*   heads  = (const int*)d_in[2];
  const float* W      = (const float*)d_in[3];
  const float* b_comp = (const float*)d_in[4];
  const float* w_red  = (const float*)d_in[5];
  const float* b_red  = (const float*)d_in[6];
  float* out = (float*)d_out;

  _Float16* W16f = (_Float16*)d_ws;  // 4 MB, MFMA-fragment order

  prep_kernel<<<3072, 256, 0, stream>>>(W, w_red, b_comp, b_red, W16f, out);
  main_kernel<<<NBLK, 512, 0, stream>>>(tok, heads, W16f, b_comp, w_red, out);
}